// Round 13
// baseline (101.586 us; speedup 1.0000x reference)
//
#include <hip/hip_runtime.h>
#include <hip/hip_bf16.h>
#include <math.h>

#define NN    8192
#define FIN   256
#define HID   64
#define NH    4
#define NC    16
#define MAXD  128
#define ALPHA 0.2f
#define KC    32

typedef float nfloat4 __attribute__((ext_vector_type(4)));
__device__ __forceinline__ float4 ldnt4(const float4* p) {
    nfloat4 v = __builtin_nontemporal_load((const nfloat4*)p);
    return make_float4(v.x, v.y, v.z, v.w);
}
__device__ __forceinline__ ushort f2bf(float x) {
    __hip_bfloat16 h = __float2bfloat16(x);
    return *reinterpret_cast<ushort*>(&h);
}
__device__ __forceinline__ float bfhi(unsigned u) { return __uint_as_float(u & 0xffff0000u); }
__device__ __forceinline__ float bflo(unsigned u) { return __uint_as_float(u << 16); }

// ---------------------------------------------------------------------------
// scan: one wave compacts one 32KB bias row into LDS colsW + global CSR.
// Returns the row degree. Non-temporal stream, 8 loads in flight.
// ---------------------------------------------------------------------------
__device__ __forceinline__ int scan_row(
    int row, int lane, int* colsW,
    const float* __restrict__ bias, int* __restrict__ deg, int* __restrict__ cols)
{
    const unsigned long long lt = (1ull << lane) - 1ull;
    colsW[lane] = 0; colsW[64 + lane] = 0;
    const float4* rp = (const float4*)(bias + (size_t)row * NN);
    float4 vv[8];
    #pragma unroll
    for (int k = 0; k < 8; ++k) vv[k] = ldnt4(rp + k*64 + lane);
    int base = 0;
    #pragma unroll
    for (int s = 0; s < 4; ++s) {
        #pragma unroll
        for (int k = 0; k < 8; ++k) {
            const float4 v = vv[k];
            if (s < 3) vv[k] = ldnt4(rp + ((s+1)*8 + k)*64 + lane);
            const unsigned long long m0 = __ballot(v.x == 0.f);
            const unsigned long long m1 = __ballot(v.y == 0.f);
            const unsigned long long m2 = __ballot(v.z == 0.f);
            const unsigned long long m3 = __ballot(v.w == 0.f);
            const int cb = ((s*8 + k)*64 + lane)*4;
            int p = base + __popcll(m0&lt) + __popcll(m1&lt)
                         + __popcll(m2&lt) + __popcll(m3&lt);
            if (v.x == 0.f) { if (p < MAXD) colsW[p] = cb;     ++p; }
            if (v.y == 0.f) { if (p < MAXD) colsW[p] = cb + 1; ++p; }
            if (v.z == 0.f) { if (p < MAXD) colsW[p] = cb + 2; ++p; }
            if (v.w == 0.f) { if (p < MAXD) colsW[p] = cb + 3; ++p; }
            base += __popcll(m0) + __popcll(m1) + __popcll(m2) + __popcll(m3);
        }
    }
    const int d = base < MAXD ? base : MAXD;
    if (lane == 0) deg[row] = d;
    cols[(size_t)row*MAXD + lane]      = colsW[lane];
    cols[(size_t)row*MAXD + 64 + lane] = colsW[64 + lane];
    return d;
}

// ---------------------------------------------------------------------------
// attn1 for one row, one wave, all 4 heads. colsW must hold the row's CSR.
// PV: one uint2/lane gather per edge = 512B bf16 block from the 4MB
// L2-resident fts1g table. Then elu/concat + fts2 = h1@W2 + g1/g2.
// ---------------------------------------------------------------------------
__device__ __forceinline__ void attn_row(
    int row, int lane, int d, int* colsW, float4* coefW, float* h1W,
    const ushort* __restrict__ fts1g, const float* __restrict__ f1v4,
    const float* __restrict__ f2v4, const float* __restrict__ bias1,
    const float* __restrict__ W2, const float* __restrict__ a2s,
    const float* __restrict__ a2d, const float* __restrict__ b2s,
    const float* __restrict__ b2d,
    float* __restrict__ fts2, float* __restrict__ g1, float* __restrict__ g2)
{
    const int c0 = colsW[lane], c1 = colsW[64 + lane];

    const float4 f1 = *(const float4*)(f1v4 + (size_t)row*NH);
    float4 s0 = make_float4(-1e30f,-1e30f,-1e30f,-1e30f), s1 = s0;
    if (lane < d) {
        const float4 F = *(const float4*)(f2v4 + (size_t)c0*NH);
        float x;
        x = f1.x + F.x; s0.x = x > 0.f ? x : ALPHA*x;
        x = f1.y + F.y; s0.y = x > 0.f ? x : ALPHA*x;
        x = f1.z + F.z; s0.z = x > 0.f ? x : ALPHA*x;
        x = f1.w + F.w; s0.w = x > 0.f ? x : ALPHA*x;
    }
    if (lane + 64 < d) {
        const float4 F = *(const float4*)(f2v4 + (size_t)c1*NH);
        float x;
        x = f1.x + F.x; s1.x = x > 0.f ? x : ALPHA*x;
        x = f1.y + F.y; s1.y = x > 0.f ? x : ALPHA*x;
        x = f1.z + F.z; s1.z = x > 0.f ? x : ALPHA*x;
        x = f1.w + F.w; s1.w = x > 0.f ? x : ALPHA*x;
    }
    float4 m;
    m.x = fmaxf(s0.x, s1.x); m.y = fmaxf(s0.y, s1.y);
    m.z = fmaxf(s0.z, s1.z); m.w = fmaxf(s0.w, s1.w);
    #pragma unroll
    for (int off = 32; off; off >>= 1) {
        m.x = fmaxf(m.x, __shfl_xor(m.x, off));
        m.y = fmaxf(m.y, __shfl_xor(m.y, off));
        m.z = fmaxf(m.z, __shfl_xor(m.z, off));
        m.w = fmaxf(m.w, __shfl_xor(m.w, off));
    }
    float4 p0 = make_float4(0,0,0,0), p1 = p0;
    if (lane < d) {
        p0.x = __expf(s0.x - m.x); p0.y = __expf(s0.y - m.y);
        p0.z = __expf(s0.z - m.z); p0.w = __expf(s0.w - m.w);
    }
    if (lane + 64 < d) {
        p1.x = __expf(s1.x - m.x); p1.y = __expf(s1.y - m.y);
        p1.z = __expf(s1.z - m.z); p1.w = __expf(s1.w - m.w);
    }
    coefW[lane] = p0; coefW[64 + lane] = p1;
    float4 sum;
    sum.x = p0.x + p1.x; sum.y = p0.y + p1.y;
    sum.z = p0.z + p1.z; sum.w = p0.w + p1.w;
    #pragma unroll
    for (int off = 32; off; off >>= 1) {
        sum.x += __shfl_xor(sum.x, off);
        sum.y += __shfl_xor(sum.y, off);
        sum.z += __shfl_xor(sum.z, off);
        sum.w += __shfl_xor(sum.w, off);
    }
    const int h = lane >> 4;
    const float invh = (h==0) ? 1.f/sum.x : (h==1) ? 1.f/sum.y
                     : (h==2) ? 1.f/sum.z : 1.f/sum.w;

    float a0 = 0.f, a1 = 0.f, a2 = 0.f, a3 = 0.f;
    #pragma unroll 8
    for (int e = 0; e < d; ++e) {
        const float4 q4 = coefW[e];
        const float cf = (h==0) ? q4.x : (h==1) ? q4.y : (h==2) ? q4.z : q4.w;
        const uint2 q = *(const uint2*)(fts1g + (size_t)colsW[e]*(NH*HID) + lane*4);
        a0 += cf * bflo(q.x); a1 += cf * bfhi(q.x);
        a2 += cf * bflo(q.y); a3 += cf * bfhi(q.y);
    }
    const float4 bv = *(const float4*)(bias1 + lane*4);
    float4 ev;
    float v;
    v = a0*invh + bv.x; ev.x = v > 0.f ? v : __expf(v) - 1.f;
    v = a1*invh + bv.y; ev.y = v > 0.f ? v : __expf(v) - 1.f;
    v = a2*invh + bv.z; ev.z = v > 0.f ? v : __expf(v) - 1.f;
    v = a3*invh + bv.w; ev.w = v > 0.f ? v : __expf(v) - 1.f;
    *(float4*)&h1W[h*68 + (lane & 15)*4] = ev;

    const int part = lane >> 4, c = lane & 15;
    float s = 0.f;
    #pragma unroll 8
    for (int q = 0; q < 64; ++q)
        s += h1W[part*68 + q] * W2[(part*64 + q)*NC + c];
    s += __shfl_xor(s, 16);
    s += __shfl_xor(s, 32);
    if (lane < NC) fts2[(size_t)row*NC + lane] = s;

    float t1 = (lane < NC) ? s * a2s[lane] : 0.f;
    float t2 = (lane < NC) ? s * a2d[lane] : 0.f;
    #pragma unroll
    for (int off = 8; off; off >>= 1) {
        t1 += __shfl_xor(t1, off);
        t2 += __shfl_xor(t2, off);
    }
    if (lane == 0) { g1[row] = t1 + b2s[0]; g2[row] = t2 + b2d[0]; }
}

// ---------------------------------------------------------------------------
// K1: gemm blocks 0..511 (dispatched first — R9's proven ordering), then
// scan blocks 512..1023 covering rows 0..2047. Gemm hides under the stream.
// ---------------------------------------------------------------------------
__global__ __launch_bounds__(256) void k_gemm_scan(
    const float* __restrict__ seq, const float* __restrict__ W1,
    const float* __restrict__ a1s, const float* __restrict__ a1d,
    const float* __restrict__ b1s, const float* __restrict__ b1d,
    const float* __restrict__ bias,
    ushort* __restrict__ fts1g, float* __restrict__ f1v, float* __restrict__ f2v,
    int* __restrict__ deg, int* __restrict__ cols)
{
    __shared__ union {
        struct { float xsT[KC][68]; float w[KC][68]; } g;
        struct { float r1[64][17];  float r2[64][17]; } gr;
        int colsS[4][MAXD];
    } S;
    const int t = threadIdx.x, bid = blockIdx.x;
    const int w = t >> 6, lane = t & 63;

    if (bid >= 512) {   // ---- scan rows 0..2047 ----
        scan_row((bid - 512)*4 + w, lane, &S.colsS[w][0], bias, deg, cols);
        return;
    }
    // ---- gemm tile: 64 nodes x 64 hid, one head ----
    const int head = bid & 3, rowbase = (bid >> 2) * 64;
    const int tr = t >> 4, tc = t & 15;

    float acc[4][4] = {};
    for (int kc = 0; kc < FIN / KC; ++kc) {
        #pragma unroll
        for (int i = 0; i < 2; ++i) {
            const int lin = t + i*256;
            const int row = lin >> 3, kq = lin & 7;
            const float4 v = *(const float4*)(seq + (size_t)(rowbase + row)*FIN + kc*KC + kq*4);
            S.g.xsT[kq*4+0][row] = v.x;
            S.g.xsT[kq*4+1][row] = v.y;
            S.g.xsT[kq*4+2][row] = v.z;
            S.g.xsT[kq*4+3][row] = v.w;
        }
        #pragma unroll
        for (int i = 0; i < 2; ++i) {
            const int lin = t + i*256;
            const int k = lin >> 4, dq = lin & 15;
            *(float4*)&S.g.w[k][dq*4] =
                *(const float4*)(W1 + ((size_t)head*FIN + kc*KC + k)*HID + dq*4);
        }
        __syncthreads();
        #pragma unroll 8
        for (int k = 0; k < KC; ++k) {
            const float4 aa = *(const float4*)&S.g.xsT[k][tr*4];
            const float4 bb = *(const float4*)&S.g.w[k][tc*4];
            acc[0][0] += aa.x*bb.x; acc[0][1] += aa.x*bb.y; acc[0][2] += aa.x*bb.z; acc[0][3] += aa.x*bb.w;
            acc[1][0] += aa.y*bb.x; acc[1][1] += aa.y*bb.y; acc[1][2] += aa.y*bb.z; acc[1][3] += aa.y*bb.w;
            acc[2][0] += aa.z*bb.x; acc[2][1] += aa.z*bb.y; acc[2][2] += aa.z*bb.z; acc[2][3] += aa.z*bb.w;
            acc[3][0] += aa.w*bb.x; acc[3][1] += aa.w*bb.y; acc[3][2] += aa.w*bb.z; acc[3][3] += aa.w*bb.w;
        }
        __syncthreads();
    }
    float p1[4], p2[4];
    #pragma unroll
    for (int i = 0; i < 4; ++i) {
        const int node = rowbase + tr*4 + i;
        ushort4 o;
        o.x = f2bf(acc[i][0]); o.y = f2bf(acc[i][1]);
        o.z = f2bf(acc[i][2]); o.w = f2bf(acc[i][3]);
        *(ushort4*)&fts1g[(size_t)node*(NH*HID) + head*HID + tc*4] = o;
        float s1 = 0.f, s2 = 0.f;
        #pragma unroll
        for (int j = 0; j < 4; ++j) {
            s1 += acc[i][j] * a1s[head*HID + tc*4 + j];
            s2 += acc[i][j] * a1d[head*HID + tc*4 + j];
        }
        p1[i] = s1; p2[i] = s2;
    }
    #pragma unroll
    for (int i = 0; i < 4; ++i) {
        S.gr.r1[tr*4 + i][tc] = p1[i];
        S.gr.r2[tr*4 + i][tc] = p2[i];
    }
    __syncthreads();
    if (t < 64) {
        float s1 = b1s[head], s2 = b1d[head];
        #pragma unroll
        for (int q = 0; q < 16; ++q) { s1 += S.gr.r1[t][q]; s2 += S.gr.r2[t][q]; }
        f1v[(rowbase + t)*NH + head] = s1;
        f2v[(rowbase + t)*NH + head] = s2;
    }
}

// ---------------------------------------------------------------------------
// K2: barrier-free FUSED kernel. bid%4!=3 -> one wave scans row (2048+f*4+w)
// then immediately runs its attention from the wave's own LDS CSR. bid%4==3
// -> attn-only for the K1-scanned rows 0..2047 (interleaved for overlap).
// Attn is L2+VALU (4MB bf16 table, XCD-L2-resident) and hides under the
// HBM-bound stream of other waves. No __syncthreads anywhere.
// ---------------------------------------------------------------------------
__global__ __launch_bounds__(256) void k_fused(
    const float* __restrict__ bias, const ushort* __restrict__ fts1g,
    const float* __restrict__ f1v4, const float* __restrict__ f2v4,
    const float* __restrict__ bias1, const float* __restrict__ W2,
    const float* __restrict__ a2s, const float* __restrict__ a2d,
    const float* __restrict__ b2s, const float* __restrict__ b2d,
    int* __restrict__ deg, int* __restrict__ cols,
    float* __restrict__ fts2, float* __restrict__ g1, float* __restrict__ g2)
{
    __shared__ int    colsS[4][MAXD];
    __shared__ float4 coefS[4][MAXD];
    __shared__ float  h1S[4][NH*68];

    const int t = threadIdx.x, bid = blockIdx.x;
    const int w = t >> 6, lane = t & 63;
    int*    colsW = &colsS[w][0];
    float4* coefW = &coefS[w][0];
    float*  h1W   = &h1S[w][0];

    const int q = bid >> 2, r = bid & 3;
    int row, d;
    if (r == 3) {
        // attn-only: rows 0..2047 (CSR from K1)
        row = q*4 + w;
        d = deg[row];
        colsW[lane]      = cols[(size_t)row*MAXD + lane];
        colsW[64 + lane] = cols[(size_t)row*MAXD + 64 + lane];
    } else {
        // fused: scan then attend
        const int f = q*3 + r;                 // 0..1535
        row = 2048 + f*4 + w;
        d = scan_row(row, lane, colsW, bias, deg, cols);
    }
    attn_row(row, lane, d, colsW, coefW, h1W,
             fts1g, f1v4, f2v4, bias1, W2, a2s, a2d, b2s, b2d,
             fts2, g1, g2);
}

// ---------------------------------------------------------------------------
// K3: layer-2 sparse attention, 1 wave/node, 4 nodes/block.
// ---------------------------------------------------------------------------
__global__ __launch_bounds__(256) void k_attn2(
    const float* __restrict__ fts2, const float* __restrict__ g1,
    const float* __restrict__ g2, const float* __restrict__ bias2,
    const int* __restrict__ deg, const int* __restrict__ cols,
    float* __restrict__ out)
{
    __shared__ int   colsS[4][MAXD];
    __shared__ float coefS[4][MAXD];
    const int t = threadIdx.x, w = t >> 6, lane = t & 63;
    const int i = blockIdx.x*4 + w;
    const int d = deg[i];
    for (int e = lane; e < MAXD; e += 64) colsS[w][e] = (e < d) ? cols[(size_t)i*MAXD + e] : 0;

    const float g1i = g1[i];
    float sc0 = -1e30f, sc1 = -1e30f;
    if (lane < d)      { const float x = g1i + g2[colsS[w][lane]];    sc0 = x > 0.f ? x : ALPHA*x; }
    if (lane + 64 < d) { const float x = g1i + g2[colsS[w][lane+64]]; sc1 = x > 0.f ? x : ALPHA*x; }
    float m = fmaxf(sc0, sc1);
    #pragma unroll
    for (int off = 32; off; off >>= 1) m = fmaxf(m, __shfl_xor(m, off));
    const float p0 = (lane      < d) ? __expf(sc0 - m) : 0.f;
    const float p1 = (lane + 64 < d) ? __expf(sc1 - m) : 0.f;
    coefS[w][lane] = p0; coefS[w][lane + 64] = p1;
    float sum = p0 + p1;
    #pragma unroll
    for (int off = 32; off; off >>= 1) sum += __shfl_xor(sum, off);
    const float inv = 1.f / sum;

    const int eg = lane >> 4, c = lane & 15;
    float acc = 0.f;
    #pragma unroll 2
    for (int e0 = 0; e0 < d; e0 += 4) {
        const int e = e0 + eg;
        if (e < d) acc += coefS[w][e] * fts2[(size_t)colsS[w][e]*NC + c];
    }
    acc += __shfl_xor(acc, 16);
    acc += __shfl_xor(acc, 32);
    if (lane < NC) out[(size_t)i*NC + lane] = acc*inv + bias2[lane];
}

// ---------------------------------------------------------------------------
extern "C" void kernel_launch(void* const* d_in, const int* in_sizes, int n_in,
                              void* d_out, int out_size, void* d_ws, size_t ws_size,
                              hipStream_t stream)
{
    const float* seq   = (const float*)d_in[0];
    const float* bias  = (const float*)d_in[1];
    const float* W1    = (const float*)d_in[2];
    const float* a1s   = (const float*)d_in[3];
    const float* a1d   = (const float*)d_in[4];
    const float* b1s   = (const float*)d_in[5];
    const float* b1d   = (const float*)d_in[6];
    const float* bias1 = (const float*)d_in[7];
    const float* W2    = (const float*)d_in[8];
    const float* a2s   = (const float*)d_in[9];
    const float* a2d   = (const float*)d_in[10];
    const float* b2s   = (const float*)d_in[11];
    const float* b2d   = (const float*)d_in[12];
    const float* bias2 = (const float*)d_in[13];

    char* ws = (char*)d_ws;
    int*    deg   = (int*)ws;    ws += (size_t)NN * 4;
    int*    cols  = (int*)ws;    ws += (size_t)NN * MAXD * 4;
    ushort* fts1g = (ushort*)ws; ws += (size_t)NN * NH * HID * 2;
    float*  f1v   = (float*)ws;  ws += (size_t)NN * NH * 4;
    float*  f2v   = (float*)ws;  ws += (size_t)NN * NH * 4;
    float*  fts2  = (float*)ws;  ws += (size_t)NN * NC * 4;
    float*  g1    = (float*)ws;  ws += (size_t)NN * 4;
    float*  g2    = (float*)ws;  ws += (size_t)NN * 4;

    hipLaunchKernelGGL(k_gemm_scan, dim3(1024), dim3(256), 0, stream,
                       seq, W1, a1s, a1d, b1s, b1d, bias,
                       fts1g, f1v, f2v, deg, cols);
    hipLaunchKernelGGL(k_fused, dim3(2048), dim3(256), 0, stream,
                       bias, fts1g, f1v, f2v, bias1, W2, a2s, a2d, b2s, b2d,
                       deg, cols, fts2, g1, g2);
    hipLaunchKernelGGL(k_attn2, dim3(NN/4), dim3(256), 0, stream,
                       fts2, g1, g2, bias2, deg, cols, (float*)d_out);
}

// Round 14
// 97.500 us; speedup vs baseline: 1.0419x; 1.0419x over previous
//
#include <hip/hip_runtime.h>
#include <hip/hip_bf16.h>
#include <math.h>

#define NN    8192
#define FIN   256
#define HID   64
#define NH    4
#define NC    16
#define MAXD  128
#define ALPHA 0.2f
#define KC    32

typedef float nfloat4 __attribute__((ext_vector_type(4)));
__device__ __forceinline__ float4 ldnt4(const float4* p) {
    nfloat4 v = __builtin_nontemporal_load((const nfloat4*)p);
    return make_float4(v.x, v.y, v.z, v.w);
}
__device__ __forceinline__ ushort f2bf(float x) {
    __hip_bfloat16 h = __float2bfloat16(x);
    return *reinterpret_cast<ushort*>(&h);
}
__device__ __forceinline__ float bfhi(unsigned u) { return __uint_as_float(u & 0xffff0000u); }
__device__ __forceinline__ float bflo(unsigned u) { return __uint_as_float(u << 16); }

// ---------------------------------------------------------------------------
// scan: one wave compacts one 32KB bias row into CSR via ballot/popcount.
// ---------------------------------------------------------------------------
__device__ __forceinline__ void scan_row(
    int row, int lane, int* colsW,
    const float* __restrict__ bias, int* __restrict__ deg, int* __restrict__ cols)
{
    const unsigned long long lt = (1ull << lane) - 1ull;
    colsW[lane] = 0; colsW[64 + lane] = 0;
    const float4* rp = (const float4*)(bias + (size_t)row * NN);
    float4 vv[8];
    #pragma unroll
    for (int k = 0; k < 8; ++k) vv[k] = ldnt4(rp + k*64 + lane);
    int base = 0;
    #pragma unroll
    for (int s = 0; s < 4; ++s) {
        #pragma unroll
        for (int k = 0; k < 8; ++k) {
            const float4 v = vv[k];
            if (s < 3) vv[k] = ldnt4(rp + ((s+1)*8 + k)*64 + lane);
            const unsigned long long m0 = __ballot(v.x == 0.f);
            const unsigned long long m1 = __ballot(v.y == 0.f);
            const unsigned long long m2 = __ballot(v.z == 0.f);
            const unsigned long long m3 = __ballot(v.w == 0.f);
            const int cb = ((s*8 + k)*64 + lane)*4;
            int p = base + __popcll(m0&lt) + __popcll(m1&lt)
                         + __popcll(m2&lt) + __popcll(m3&lt);
            if (v.x == 0.f) { if (p < MAXD) colsW[p] = cb;     ++p; }
            if (v.y == 0.f) { if (p < MAXD) colsW[p] = cb + 1; ++p; }
            if (v.z == 0.f) { if (p < MAXD) colsW[p] = cb + 2; ++p; }
            if (v.w == 0.f) { if (p < MAXD) colsW[p] = cb + 3; ++p; }
            base += __popcll(m0) + __popcll(m1) + __popcll(m2) + __popcll(m3);
        }
    }
    const int d = base < MAXD ? base : MAXD;
    if (lane == 0) deg[row] = d;
    cols[(size_t)row*MAXD + lane]      = colsW[lane];
    cols[(size_t)row*MAXD + 64 + lane] = colsW[64 + lane];
}

// ---------------------------------------------------------------------------
// K1 (R9's proven structure): gemm blocks 0..511 first, scan blocks 512..2559
// cover all 8192 rows. Gemm (LDS/VALU) hides under the HBM-bound scan.
// ---------------------------------------------------------------------------
__global__ __launch_bounds__(256) void k_gemm_scan(
    const float* __restrict__ seq, const float* __restrict__ W1,
    const float* __restrict__ a1s, const float* __restrict__ a1d,
    const float* __restrict__ b1s, const float* __restrict__ b1d,
    const float* __restrict__ bias,
    ushort* __restrict__ fts1g, float* __restrict__ f1v, float* __restrict__ f2v,
    int* __restrict__ deg, int* __restrict__ cols)
{
    __shared__ union {
        struct { float xsT[KC][68]; float w[KC][68]; } g;
        struct { float r1[64][17];  float r2[64][17]; } gr;
        int colsS[4][MAXD];
    } S;
    const int t = threadIdx.x, bid = blockIdx.x;
    const int w = t >> 6, lane = t & 63;

    if (bid >= 512) {   // ---- scan ----
        scan_row((bid - 512)*4 + w, lane, &S.colsS[w][0], bias, deg, cols);
        return;
    }
    // ---- gemm tile: 64 nodes x 64 hid, one head ----
    const int head = bid & 3, rowbase = (bid >> 2) * 64;
    const int tr = t >> 4, tc = t & 15;

    float acc[4][4] = {};
    for (int kc = 0; kc < FIN / KC; ++kc) {
        #pragma unroll
        for (int i = 0; i < 2; ++i) {
            const int lin = t + i*256;
            const int row = lin >> 3, kq = lin & 7;
            const float4 v = *(const float4*)(seq + (size_t)(rowbase + row)*FIN + kc*KC + kq*4);
            S.g.xsT[kq*4+0][row] = v.x;
            S.g.xsT[kq*4+1][row] = v.y;
            S.g.xsT[kq*4+2][row] = v.z;
            S.g.xsT[kq*4+3][row] = v.w;
        }
        #pragma unroll
        for (int i = 0; i < 2; ++i) {
            const int lin = t + i*256;
            const int k = lin >> 4, dq = lin & 15;
            *(float4*)&S.g.w[k][dq*4] =
                *(const float4*)(W1 + ((size_t)head*FIN + kc*KC + k)*HID + dq*4);
        }
        __syncthreads();
        #pragma unroll 8
        for (int k = 0; k < KC; ++k) {
            const float4 aa = *(const float4*)&S.g.xsT[k][tr*4];
            const float4 bb = *(const float4*)&S.g.w[k][tc*4];
            acc[0][0] += aa.x*bb.x; acc[0][1] += aa.x*bb.y; acc[0][2] += aa.x*bb.z; acc[0][3] += aa.x*bb.w;
            acc[1][0] += aa.y*bb.x; acc[1][1] += aa.y*bb.y; acc[1][2] += aa.y*bb.z; acc[1][3] += aa.y*bb.w;
            acc[2][0] += aa.z*bb.x; acc[2][1] += aa.z*bb.y; acc[2][2] += aa.z*bb.z; acc[2][3] += aa.z*bb.w;
            acc[3][0] += aa.w*bb.x; acc[3][1] += aa.w*bb.y; acc[3][2] += aa.w*bb.z; acc[3][3] += aa.w*bb.w;
        }
        __syncthreads();
    }
    float p1[4], p2[4];
    #pragma unroll
    for (int i = 0; i < 4; ++i) {
        const int node = rowbase + tr*4 + i;
        ushort4 o;
        o.x = f2bf(acc[i][0]); o.y = f2bf(acc[i][1]);
        o.z = f2bf(acc[i][2]); o.w = f2bf(acc[i][3]);
        *(ushort4*)&fts1g[(size_t)node*(NH*HID) + head*HID + tc*4] = o;
        float s1 = 0.f, s2 = 0.f;
        #pragma unroll
        for (int j = 0; j < 4; ++j) {
            s1 += acc[i][j] * a1s[head*HID + tc*4 + j];
            s2 += acc[i][j] * a1d[head*HID + tc*4 + j];
        }
        p1[i] = s1; p2[i] = s2;
    }
    #pragma unroll
    for (int i = 0; i < 4; ++i) {
        S.gr.r1[tr*4 + i][tc] = p1[i];
        S.gr.r2[tr*4 + i][tc] = p2[i];
    }
    __syncthreads();
    if (t < 64) {
        float s1 = b1s[head], s2 = b1d[head];
        #pragma unroll
        for (int q = 0; q < 16; ++q) { s1 += S.gr.r1[t][q]; s2 += S.gr.r2[t][q]; }
        f1v[(rowbase + t)*NH + head] = s1;
        f2v[(rowbase + t)*NH + head] = s2;
    }
}

// ---------------------------------------------------------------------------
// K2: layer-1 attention, TWO WAVES PER ROW (edges interleaved mod 2), 2 rows
// per 256-thread block. Doubles per-row memory-level parallelism: each wave
// serializes only ~d/2 L3 gathers; 16384 waves total. Partial max/sum/acc
// exchanged via LDS with block barriers. Even wave runs the epilogue.
// ---------------------------------------------------------------------------
__global__ __launch_bounds__(256) void k_attn1(
    const ushort* __restrict__ fts1g, const float* __restrict__ f1v4,
    const float* __restrict__ f2v4, const float* __restrict__ bias1,
    const float* __restrict__ W2, const float* __restrict__ a2s,
    const float* __restrict__ a2d, const float* __restrict__ b2s,
    const float* __restrict__ b2d,
    const int* __restrict__ deg, const int* __restrict__ cols,
    float* __restrict__ fts2, float* __restrict__ g1, float* __restrict__ g2)
{
    __shared__ int    colsS[2][MAXD];
    __shared__ float4 coefS[2][MAXD];
    __shared__ float4 mS[2][2];
    __shared__ float4 sS[2][2];
    __shared__ float4 accS[2][64];
    __shared__ float  h1S[2][NH*68];

    const int t = threadIdx.x, w = t >> 6, lane = t & 63;
    const int rw = w >> 1, half = w & 1;
    const int row = blockIdx.x*2 + rw;
    const int h = lane >> 4;

    const int d = deg[row];
    colsS[rw][half*64 + lane] = cols[(size_t)row*MAXD + half*64 + lane];
    __syncthreads();

    // ---- scores: lane owns edge e0 = 2*lane + half ----
    const int e0 = 2*lane + half;
    const float4 f1 = *(const float4*)(f1v4 + (size_t)row*NH);
    float4 s0 = make_float4(-1e30f,-1e30f,-1e30f,-1e30f);
    if (e0 < d) {
        const float4 F = *(const float4*)(f2v4 + (size_t)colsS[rw][e0]*NH);
        float x;
        x = f1.x + F.x; s0.x = x > 0.f ? x : ALPHA*x;
        x = f1.y + F.y; s0.y = x > 0.f ? x : ALPHA*x;
        x = f1.z + F.z; s0.z = x > 0.f ? x : ALPHA*x;
        x = f1.w + F.w; s0.w = x > 0.f ? x : ALPHA*x;
    }
    float4 m = s0;
    #pragma unroll
    for (int off = 32; off; off >>= 1) {
        m.x = fmaxf(m.x, __shfl_xor(m.x, off));
        m.y = fmaxf(m.y, __shfl_xor(m.y, off));
        m.z = fmaxf(m.z, __shfl_xor(m.z, off));
        m.w = fmaxf(m.w, __shfl_xor(m.w, off));
    }
    if (lane == 0) mS[rw][half] = m;
    __syncthreads();
    {
        const float4 mA = mS[rw][0], mB = mS[rw][1];
        m.x = fmaxf(mA.x, mB.x); m.y = fmaxf(mA.y, mB.y);
        m.z = fmaxf(mA.z, mB.z); m.w = fmaxf(mA.w, mB.w);
    }
    float4 p = make_float4(0,0,0,0);
    if (e0 < d) {
        p.x = __expf(s0.x - m.x); p.y = __expf(s0.y - m.y);
        p.z = __expf(s0.z - m.z); p.w = __expf(s0.w - m.w);
    }
    coefS[rw][e0] = p;
    float4 sum = p;
    #pragma unroll
    for (int off = 32; off; off >>= 1) {
        sum.x += __shfl_xor(sum.x, off);
        sum.y += __shfl_xor(sum.y, off);
        sum.z += __shfl_xor(sum.z, off);
        sum.w += __shfl_xor(sum.w, off);
    }
    if (lane == 0) sS[rw][half] = sum;
    __syncthreads();
    {
        const float4 sA = sS[rw][0], sB = sS[rw][1];
        sum.x = sA.x + sB.x; sum.y = sA.y + sB.y;
        sum.z = sA.z + sB.z; sum.w = sA.w + sB.w;
    }
    const float invh = (h==0) ? 1.f/sum.x : (h==1) ? 1.f/sum.y
                     : (h==2) ? 1.f/sum.z : 1.f/sum.w;

    // ---- PV: wave `half` handles edges e = half, half+2, ... ----
    float a0 = 0.f, a1 = 0.f, a2 = 0.f, a3 = 0.f;
    #pragma unroll 8
    for (int e = half; e < d; e += 2) {
        const float4 q4 = coefS[rw][e];
        const float cf = (h==0) ? q4.x : (h==1) ? q4.y : (h==2) ? q4.z : q4.w;
        const uint2 q = *(const uint2*)(fts1g + (size_t)colsS[rw][e]*(NH*HID) + lane*4);
        a0 += cf * bflo(q.x); a1 += cf * bfhi(q.x);
        a2 += cf * bflo(q.y); a3 += cf * bfhi(q.y);
    }
    if (half == 1) accS[rw][lane] = make_float4(a0, a1, a2, a3);
    __syncthreads();
    if (half == 1) return;

    {
        const float4 o = accS[rw][lane];
        a0 += o.x; a1 += o.y; a2 += o.z; a3 += o.w;
    }
    const float4 bv = *(const float4*)(bias1 + lane*4);
    float4 ev;
    float v;
    v = a0*invh + bv.x; ev.x = v > 0.f ? v : __expf(v) - 1.f;
    v = a1*invh + bv.y; ev.y = v > 0.f ? v : __expf(v) - 1.f;
    v = a2*invh + bv.z; ev.z = v > 0.f ? v : __expf(v) - 1.f;
    v = a3*invh + bv.w; ev.w = v > 0.f ? v : __expf(v) - 1.f;
    *(float4*)&h1S[rw][h*68 + (lane & 15)*4] = ev;   // same-wave produce/consume

    const int part = lane >> 4, c = lane & 15;
    float s = 0.f;
    #pragma unroll 8
    for (int q = 0; q < 64; ++q)
        s += h1S[rw][part*68 + q] * W2[(part*64 + q)*NC + c];
    s += __shfl_xor(s, 16);
    s += __shfl_xor(s, 32);
    if (lane < NC) fts2[(size_t)row*NC + lane] = s;

    float t1 = (lane < NC) ? s * a2s[lane] : 0.f;
    float t2 = (lane < NC) ? s * a2d[lane] : 0.f;
    #pragma unroll
    for (int off = 8; off; off >>= 1) {
        t1 += __shfl_xor(t1, off);
        t2 += __shfl_xor(t2, off);
    }
    if (lane == 0) { g1[row] = t1 + b2s[0]; g2[row] = t2 + b2d[0]; }
}

// ---------------------------------------------------------------------------
// K3: layer-2 sparse attention, 1 wave/node, 4 nodes/block.
// ---------------------------------------------------------------------------
__global__ __launch_bounds__(256) void k_attn2(
    const float* __restrict__ fts2, const float* __restrict__ g1,
    const float* __restrict__ g2, const float* __restrict__ bias2,
    const int* __restrict__ deg, const int* __restrict__ cols,
    float* __restrict__ out)
{
    __shared__ int   colsS[4][MAXD];
    __shared__ float coefS[4][MAXD];
    const int t = threadIdx.x, w = t >> 6, lane = t & 63;
    const int i = blockIdx.x*4 + w;
    const int d = deg[i];
    for (int e = lane; e < MAXD; e += 64) colsS[w][e] = (e < d) ? cols[(size_t)i*MAXD + e] : 0;

    const float g1i = g1[i];
    float sc0 = -1e30f, sc1 = -1e30f;
    if (lane < d)      { const float x = g1i + g2[colsS[w][lane]];    sc0 = x > 0.f ? x : ALPHA*x; }
    if (lane + 64 < d) { const float x = g1i + g2[colsS[w][lane+64]]; sc1 = x > 0.f ? x : ALPHA*x; }
    float m = fmaxf(sc0, sc1);
    #pragma unroll
    for (int off = 32; off; off >>= 1) m = fmaxf(m, __shfl_xor(m, off));
    const float p0 = (lane      < d) ? __expf(sc0 - m) : 0.f;
    const float p1 = (lane + 64 < d) ? __expf(sc1 - m) : 0.f;
    coefS[w][lane] = p0; coefS[w][lane + 64] = p1;
    float sum = p0 + p1;
    #pragma unroll
    for (int off = 32; off; off >>= 1) sum += __shfl_xor(sum, off);
    const float inv = 1.f / sum;

    const int eg = lane >> 4, c = lane & 15;
    float acc = 0.f;
    #pragma unroll 2
    for (int e0 = 0; e0 < d; e0 += 4) {
        const int e = e0 + eg;
        if (e < d) acc += coefS[w][e] * fts2[(size_t)colsS[w][e]*NC + c];
    }
    acc += __shfl_xor(acc, 16);
    acc += __shfl_xor(acc, 32);
    if (lane < NC) out[(size_t)i*NC + lane] = acc*inv + bias2[lane];
}

// ---------------------------------------------------------------------------
extern "C" void kernel_launch(void* const* d_in, const int* in_sizes, int n_in,
                              void* d_out, int out_size, void* d_ws, size_t ws_size,
                              hipStream_t stream)
{
    const float* seq   = (const float*)d_in[0];
    const float* bias  = (const float*)d_in[1];
    const float* W1    = (const float*)d_in[2];
    const float* a1s   = (const float*)d_in[3];
    const float* a1d   = (const float*)d_in[4];
    const float* b1s   = (const float*)d_in[5];
    const float* b1d   = (const float*)d_in[6];
    const float* bias1 = (const float*)d_in[7];
    const float* W2    = (const float*)d_in[8];
    const float* a2s   = (const float*)d_in[9];
    const float* a2d   = (const float*)d_in[10];
    const float* b2s   = (const float*)d_in[11];
    const float* b2d   = (const float*)d_in[12];
    const float* bias2 = (const float*)d_in[13];

    char* ws = (char*)d_ws;
    int*    deg   = (int*)ws;    ws += (size_t)NN * 4;
    int*    cols  = (int*)ws;    ws += (size_t)NN * MAXD * 4;
    ushort* fts1g = (ushort*)ws; ws += (size_t)NN * NH * HID * 2;
    float*  f1v   = (float*)ws;  ws += (size_t)NN * NH * 4;
    float*  f2v   = (float*)ws;  ws += (size_t)NN * NH * 4;
    float*  fts2  = (float*)ws;  ws += (size_t)NN * NC * 4;
    float*  g1    = (float*)ws;  ws += (size_t)NN * 4;
    float*  g2    = (float*)ws;  ws += (size_t)NN * 4;

    hipLaunchKernelGGL(k_gemm_scan, dim3(512 + NN/4), dim3(256), 0, stream,
                       seq, W1, a1s, a1d, b1s, b1d, bias,
                       fts1g, f1v, f2v, deg, cols);
    hipLaunchKernelGGL(k_attn1, dim3(NN/2), dim3(256), 0, stream,
                       fts1g, f1v, f2v, bias1, W2, a2s, a2d, b2s, b2d,
                       deg, cols, fts2, g1, g2);
    hipLaunchKernelGGL(k_attn2, dim3(NN/4), dim3(256), 0, stream,
                       fts2, g1, g2, bias2, deg, cols, (float*)d_out);
}

// Round 15
// 91.873 us; speedup vs baseline: 1.1057x; 1.0612x over previous
//
#include <hip/hip_runtime.h>
#include <hip/hip_bf16.h>
#include <math.h>

#define NN    8192
#define FIN   256
#define HID   64
#define NH    4
#define NC    16
#define MAXD  128
#define ALPHA 0.2f
#define KC    32

typedef float nfloat4 __attribute__((ext_vector_type(4)));
__device__ __forceinline__ float4 ldnt4(const float4* p) {
    nfloat4 v = __builtin_nontemporal_load((const nfloat4*)p);
    return make_float4(v.x, v.y, v.z, v.w);
}
__device__ __forceinline__ ushort f2bf(float x) {
    __hip_bfloat16 h = __float2bfloat16(x);
    return *reinterpret_cast<ushort*>(&h);
}
__device__ __forceinline__ float bfhi(unsigned u) { return __uint_as_float(u & 0xffff0000u); }
__device__ __forceinline__ float bflo(unsigned u) { return __uint_as_float(u << 16); }

// ---------------------------------------------------------------------------
// scan: one wave compacts one 32KB bias row into CSR via ballot/popcount.
// ---------------------------------------------------------------------------
__device__ __forceinline__ void scan_row(
    int row, int lane, int* colsW,
    const float* __restrict__ bias, int* __restrict__ deg, int* __restrict__ cols)
{
    const unsigned long long lt = (1ull << lane) - 1ull;
    colsW[lane] = 0; colsW[64 + lane] = 0;
    const float4* rp = (const float4*)(bias + (size_t)row * NN);
    float4 vv[8];
    #pragma unroll
    for (int k = 0; k < 8; ++k) vv[k] = ldnt4(rp + k*64 + lane);
    int base = 0;
    #pragma unroll
    for (int s = 0; s < 4; ++s) {
        #pragma unroll
        for (int k = 0; k < 8; ++k) {
            const float4 v = vv[k];
            if (s < 3) vv[k] = ldnt4(rp + ((s+1)*8 + k)*64 + lane);
            const unsigned long long m0 = __ballot(v.x == 0.f);
            const unsigned long long m1 = __ballot(v.y == 0.f);
            const unsigned long long m2 = __ballot(v.z == 0.f);
            const unsigned long long m3 = __ballot(v.w == 0.f);
            const int cb = ((s*8 + k)*64 + lane)*4;
            int p = base + __popcll(m0&lt) + __popcll(m1&lt)
                         + __popcll(m2&lt) + __popcll(m3&lt);
            if (v.x == 0.f) { if (p < MAXD) colsW[p] = cb;     ++p; }
            if (v.y == 0.f) { if (p < MAXD) colsW[p] = cb + 1; ++p; }
            if (v.z == 0.f) { if (p < MAXD) colsW[p] = cb + 2; ++p; }
            if (v.w == 0.f) { if (p < MAXD) colsW[p] = cb + 3; ++p; }
            base += __popcll(m0) + __popcll(m1) + __popcll(m2) + __popcll(m3);
        }
    }
    const int d = base < MAXD ? base : MAXD;
    if (lane == 0) deg[row] = d;
    cols[(size_t)row*MAXD + lane]      = colsW[lane];
    cols[(size_t)row*MAXD + 64 + lane] = colsW[64 + lane];
}

// ---------------------------------------------------------------------------
// K1 (R9's proven structure): gemm blocks 0..511 first, scan blocks 512..2559
// cover all 8192 rows. Gemm (LDS/VALU) hides under the HBM-bound scan.
// ---------------------------------------------------------------------------
__global__ __launch_bounds__(256) void k_gemm_scan(
    const float* __restrict__ seq, const float* __restrict__ W1,
    const float* __restrict__ a1s, const float* __restrict__ a1d,
    const float* __restrict__ b1s, const float* __restrict__ b1d,
    const float* __restrict__ bias,
    ushort* __restrict__ fts1g, float* __restrict__ f1v, float* __restrict__ f2v,
    int* __restrict__ deg, int* __restrict__ cols)
{
    __shared__ union {
        struct { float xsT[KC][68]; float w[KC][68]; } g;
        struct { float r1[64][17];  float r2[64][17]; } gr;
        int colsS[4][MAXD];
    } S;
    const int t = threadIdx.x, bid = blockIdx.x;
    const int w = t >> 6, lane = t & 63;

    if (bid >= 512) {   // ---- scan ----
        scan_row((bid - 512)*4 + w, lane, &S.colsS[w][0], bias, deg, cols);
        return;
    }
    // ---- gemm tile: 64 nodes x 64 hid, one head ----
    const int head = bid & 3, rowbase = (bid >> 2) * 64;
    const int tr = t >> 4, tc = t & 15;

    float acc[4][4] = {};
    for (int kc = 0; kc < FIN / KC; ++kc) {
        #pragma unroll
        for (int i = 0; i < 2; ++i) {
            const int lin = t + i*256;
            const int row = lin >> 3, kq = lin & 7;
            const float4 v = *(const float4*)(seq + (size_t)(rowbase + row)*FIN + kc*KC + kq*4);
            S.g.xsT[kq*4+0][row] = v.x;
            S.g.xsT[kq*4+1][row] = v.y;
            S.g.xsT[kq*4+2][row] = v.z;
            S.g.xsT[kq*4+3][row] = v.w;
        }
        #pragma unroll
        for (int i = 0; i < 2; ++i) {
            const int lin = t + i*256;
            const int k = lin >> 4, dq = lin & 15;
            *(float4*)&S.g.w[k][dq*4] =
                *(const float4*)(W1 + ((size_t)head*FIN + kc*KC + k)*HID + dq*4);
        }
        __syncthreads();
        #pragma unroll 8
        for (int k = 0; k < KC; ++k) {
            const float4 aa = *(const float4*)&S.g.xsT[k][tr*4];
            const float4 bb = *(const float4*)&S.g.w[k][tc*4];
            acc[0][0] += aa.x*bb.x; acc[0][1] += aa.x*bb.y; acc[0][2] += aa.x*bb.z; acc[0][3] += aa.x*bb.w;
            acc[1][0] += aa.y*bb.x; acc[1][1] += aa.y*bb.y; acc[1][2] += aa.y*bb.z; acc[1][3] += aa.y*bb.w;
            acc[2][0] += aa.z*bb.x; acc[2][1] += aa.z*bb.y; acc[2][2] += aa.z*bb.z; acc[2][3] += aa.z*bb.w;
            acc[3][0] += aa.w*bb.x; acc[3][1] += aa.w*bb.y; acc[3][2] += aa.w*bb.z; acc[3][3] += aa.w*bb.w;
        }
        __syncthreads();
    }
    float p1[4], p2[4];
    #pragma unroll
    for (int i = 0; i < 4; ++i) {
        const int node = rowbase + tr*4 + i;
        ushort4 o;
        o.x = f2bf(acc[i][0]); o.y = f2bf(acc[i][1]);
        o.z = f2bf(acc[i][2]); o.w = f2bf(acc[i][3]);
        *(ushort4*)&fts1g[(size_t)node*(NH*HID) + head*HID + tc*4] = o;
        float s1 = 0.f, s2 = 0.f;
        #pragma unroll
        for (int j = 0; j < 4; ++j) {
            s1 += acc[i][j] * a1s[head*HID + tc*4 + j];
            s2 += acc[i][j] * a1d[head*HID + tc*4 + j];
        }
        p1[i] = s1; p2[i] = s2;
    }
    #pragma unroll
    for (int i = 0; i < 4; ++i) {
        S.gr.r1[tr*4 + i][tc] = p1[i];
        S.gr.r2[tr*4 + i][tc] = p2[i];
    }
    __syncthreads();
    if (t < 64) {
        float s1 = b1s[head], s2 = b1d[head];
        #pragma unroll
        for (int q = 0; q < 16; ++q) { s1 += S.gr.r1[t][q]; s2 += S.gr.r2[t][q]; }
        f1v[(rowbase + t)*NH + head] = s1;
        f2v[(rowbase + t)*NH + head] = s2;
    }
}

// ---------------------------------------------------------------------------
// K2: layer-1 attention, ONE WAVE PER ROW (all 4 heads), 4 rows/block.
// R9's exact structure; only transcendentals swapped to __expf.
// ---------------------------------------------------------------------------
__global__ __launch_bounds__(256) void k_attn1(
    const ushort* __restrict__ fts1g, const float* __restrict__ f1v4,
    const float* __restrict__ f2v4, const float* __restrict__ bias1,
    const float* __restrict__ W2, const float* __restrict__ a2s,
    const float* __restrict__ a2d, const float* __restrict__ b2s,
    const float* __restrict__ b2d,
    const int* __restrict__ deg, const int* __restrict__ cols,
    float* __restrict__ fts2, float* __restrict__ g1, float* __restrict__ g2)
{
    __shared__ int    colsS[4][MAXD];
    __shared__ float4 coefS[4][MAXD];
    __shared__ float  h1S[4][NH*68];

    const int t = threadIdx.x, w = t >> 6, lane = t & 63;
    const int row = blockIdx.x*4 + w;
    int*    colsW = &colsS[w][0];
    float4* coefW = &coefS[w][0];
    float*  h1W   = &h1S[w][0];

    const int d = deg[row];
    const int c0 = cols[(size_t)row*MAXD + lane];
    const int c1 = cols[(size_t)row*MAXD + 64 + lane];
    colsW[lane] = c0; colsW[64 + lane] = c1;

    // scores: one float4 f2v gather per edge serves all 4 heads
    const float4 f1 = *(const float4*)(f1v4 + (size_t)row*NH);
    float4 s0 = make_float4(-1e30f,-1e30f,-1e30f,-1e30f), s1 = s0;
    if (lane < d) {
        const float4 F = *(const float4*)(f2v4 + (size_t)c0*NH);
        float x;
        x = f1.x + F.x; s0.x = x > 0.f ? x : ALPHA*x;
        x = f1.y + F.y; s0.y = x > 0.f ? x : ALPHA*x;
        x = f1.z + F.z; s0.z = x > 0.f ? x : ALPHA*x;
        x = f1.w + F.w; s0.w = x > 0.f ? x : ALPHA*x;
    }
    if (lane + 64 < d) {
        const float4 F = *(const float4*)(f2v4 + (size_t)c1*NH);
        float x;
        x = f1.x + F.x; s1.x = x > 0.f ? x : ALPHA*x;
        x = f1.y + F.y; s1.y = x > 0.f ? x : ALPHA*x;
        x = f1.z + F.z; s1.z = x > 0.f ? x : ALPHA*x;
        x = f1.w + F.w; s1.w = x > 0.f ? x : ALPHA*x;
    }
    float4 m;
    m.x = fmaxf(s0.x, s1.x); m.y = fmaxf(s0.y, s1.y);
    m.z = fmaxf(s0.z, s1.z); m.w = fmaxf(s0.w, s1.w);
    #pragma unroll
    for (int off = 32; off; off >>= 1) {
        m.x = fmaxf(m.x, __shfl_xor(m.x, off));
        m.y = fmaxf(m.y, __shfl_xor(m.y, off));
        m.z = fmaxf(m.z, __shfl_xor(m.z, off));
        m.w = fmaxf(m.w, __shfl_xor(m.w, off));
    }
    float4 p0 = make_float4(0,0,0,0), p1 = p0;
    if (lane < d) {
        p0.x = __expf(s0.x - m.x); p0.y = __expf(s0.y - m.y);
        p0.z = __expf(s0.z - m.z); p0.w = __expf(s0.w - m.w);
    }
    if (lane + 64 < d) {
        p1.x = __expf(s1.x - m.x); p1.y = __expf(s1.y - m.y);
        p1.z = __expf(s1.z - m.z); p1.w = __expf(s1.w - m.w);
    }
    coefW[lane] = p0; coefW[64 + lane] = p1;
    float4 sum;
    sum.x = p0.x + p1.x; sum.y = p0.y + p1.y;
    sum.z = p0.z + p1.z; sum.w = p0.w + p1.w;
    #pragma unroll
    for (int off = 32; off; off >>= 1) {
        sum.x += __shfl_xor(sum.x, off);
        sum.y += __shfl_xor(sum.y, off);
        sum.z += __shfl_xor(sum.z, off);
        sum.w += __shfl_xor(sum.w, off);
    }
    const int h = lane >> 4;
    const float invh = (h==0) ? 1.f/sum.x : (h==1) ? 1.f/sum.y
                     : (h==2) ? 1.f/sum.z : 1.f/sum.w;

    // PV: lane owns (head=l>>4, dims (l&15)*4..+3) = ushort offset l*4
    float a0 = 0.f, a1 = 0.f, a2 = 0.f, a3 = 0.f;
    #pragma unroll 8
    for (int e = 0; e < d; ++e) {
        const float4 q4 = coefW[e];
        const float cf = (h==0) ? q4.x : (h==1) ? q4.y : (h==2) ? q4.z : q4.w;
        const uint2 q = *(const uint2*)(fts1g + (size_t)colsW[e]*(NH*HID) + lane*4);
        a0 += cf * bflo(q.x); a1 += cf * bfhi(q.x);
        a2 += cf * bflo(q.y); a3 += cf * bfhi(q.y);
    }
    const float4 bv = *(const float4*)(bias1 + lane*4);
    float4 ev;
    float v;
    v = a0*invh + bv.x; ev.x = v > 0.f ? v : __expf(v) - 1.f;
    v = a1*invh + bv.y; ev.y = v > 0.f ? v : __expf(v) - 1.f;
    v = a2*invh + bv.z; ev.z = v > 0.f ? v : __expf(v) - 1.f;
    v = a3*invh + bv.w; ev.w = v > 0.f ? v : __expf(v) - 1.f;
    *(float4*)&h1W[h*68 + (lane & 15)*4] = ev;

    // fts2 = h1 @ W2 ([256]x[256,16]); W2 16KB L1-resident
    const int part = lane >> 4, c = lane & 15;
    float s = 0.f;
    #pragma unroll 8
    for (int q = 0; q < 64; ++q)
        s += h1W[part*68 + q] * W2[(part*64 + q)*NC + c];
    s += __shfl_xor(s, 16);
    s += __shfl_xor(s, 32);
    if (lane < NC) fts2[(size_t)row*NC + lane] = s;

    float t1 = (lane < NC) ? s * a2s[lane] : 0.f;
    float t2 = (lane < NC) ? s * a2d[lane] : 0.f;
    #pragma unroll
    for (int off = 8; off; off >>= 1) {
        t1 += __shfl_xor(t1, off);
        t2 += __shfl_xor(t2, off);
    }
    if (lane == 0) { g1[row] = t1 + b2s[0]; g2[row] = t2 + b2d[0]; }
}

// ---------------------------------------------------------------------------
// K3: layer-2 sparse attention, 1 wave/node, 4 nodes/block.
// ---------------------------------------------------------------------------
__global__ __launch_bounds__(256) void k_attn2(
    const float* __restrict__ fts2, const float* __restrict__ g1,
    const float* __restrict__ g2, const float* __restrict__ bias2,
    const int* __restrict__ deg, const int* __restrict__ cols,
    float* __restrict__ out)
{
    __shared__ int   colsS[4][MAXD];
    __shared__ float coefS[4][MAXD];
    const int t = threadIdx.x, w = t >> 6, lane = t & 63;
    const int i = blockIdx.x*4 + w;
    const int d = deg[i];
    for (int e = lane; e < MAXD; e += 64) colsS[w][e] = (e < d) ? cols[(size_t)i*MAXD + e] : 0;

    const float g1i = g1[i];
    float sc0 = -1e30f, sc1 = -1e30f;
    if (lane < d)      { const float x = g1i + g2[colsS[w][lane]];    sc0 = x > 0.f ? x : ALPHA*x; }
    if (lane + 64 < d) { const float x = g1i + g2[colsS[w][lane+64]]; sc1 = x > 0.f ? x : ALPHA*x; }
    float m = fmaxf(sc0, sc1);
    #pragma unroll
    for (int off = 32; off; off >>= 1) m = fmaxf(m, __shfl_xor(m, off));
    const float p0 = (lane      < d) ? __expf(sc0 - m) : 0.f;
    const float p1 = (lane + 64 < d) ? __expf(sc1 - m) : 0.f;
    coefS[w][lane] = p0; coefS[w][lane + 64] = p1;
    float sum = p0 + p1;
    #pragma unroll
    for (int off = 32; off; off >>= 1) sum += __shfl_xor(sum, off);
    const float inv = 1.f / sum;

    const int eg = lane >> 4, c = lane & 15;
    float acc = 0.f;
    #pragma unroll 2
    for (int e0 = 0; e0 < d; e0 += 4) {
        const int e = e0 + eg;
        if (e < d) acc += coefS[w][e] * fts2[(size_t)colsS[w][e]*NC + c];
    }
    acc += __shfl_xor(acc, 16);
    acc += __shfl_xor(acc, 32);
    if (lane < NC) out[(size_t)i*NC + lane] = acc*inv + bias2[lane];
}

// ---------------------------------------------------------------------------
extern "C" void kernel_launch(void* const* d_in, const int* in_sizes, int n_in,
                              void* d_out, int out_size, void* d_ws, size_t ws_size,
                              hipStream_t stream)
{
    const float* seq   = (const float*)d_in[0];
    const float* bias  = (const float*)d_in[1];
    const float* W1    = (const float*)d_in[2];
    const float* a1s   = (const float*)d_in[3];
    const float* a1d   = (const float*)d_in[4];
    const float* b1s   = (const float*)d_in[5];
    const float* b1d   = (const float*)d_in[6];
    const float* bias1 = (const float*)d_in[7];
    const float* W2    = (const float*)d_in[8];
    const float* a2s   = (const float*)d_in[9];
    const float* a2d   = (const float*)d_in[10];
    const float* b2s   = (const float*)d_in[11];
    const float* b2d   = (const float*)d_in[12];
    const float* bias2 = (const float*)d_in[13];

    char* ws = (char*)d_ws;
    int*    deg   = (int*)ws;    ws += (size_t)NN * 4;
    int*    cols  = (int*)ws;    ws += (size_t)NN * MAXD * 4;
    ushort* fts1g = (ushort*)ws; ws += (size_t)NN * NH * HID * 2;
    float*  f1v   = (float*)ws;  ws += (size_t)NN * NH * 4;
    float*  f2v   = (float*)ws;  ws += (size_t)NN * NH * 4;
    float*  fts2  = (float*)ws;  ws += (size_t)NN * NC * 4;
    float*  g1    = (float*)ws;  ws += (size_t)NN * 4;
    float*  g2    = (float*)ws;  ws += (size_t)NN * 4;

    hipLaunchKernelGGL(k_gemm_scan, dim3(512 + NN/4), dim3(256), 0, stream,
                       seq, W1, a1s, a1d, b1s, b1d, bias,
                       fts1g, f1v, f2v, deg, cols);
    hipLaunchKernelGGL(k_attn1, dim3(NN/4), dim3(256), 0, stream,
                       fts1g, f1v, f2v, bias1, W2, a2s, a2d, b2s, b2d,
                       deg, cols, fts2, g1, g2);
    hipLaunchKernelGGL(k_attn2, dim3(NN/4), dim3(256), 0, stream,
                       fts2, g1, g2, bias2, deg, cols, (float*)d_out);
}